// Round 1
// baseline (1715.115 us; speedup 1.0000x reference)
//
#include <hip/hip_runtime.h>
#include <math.h>

#define HIDN 320
#define DIMN 64

// workspace float layout
#define W1T_OFF 0          // [64][320]   w1t[i][h'] = (M1*W1)[perm1[h'], i]
#define W2T_OFF 20480      // [320][320]  w2t[h'][g'] = (M2*W2)[perm2[g'], perm1[h']]
#define W3I_OFF 122880     // [64][320][2] interleaved {s-row i, t-row i+64} at perm2[g']
#define B1P_OFF 163840     // [320] b1[perm1]
#define B2P_OFF 164160     // [320] b2[perm2]
#define FTOT    164480
// workspace int layout (after floats): perm1[320] perm2[320] start1[65] start2[65]

__global__ __launch_bounds__(320) void maf_setup(const float* __restrict__ M1,
                                                 const float* __restrict__ M3,
                                                 int* __restrict__ wsi) {
  __shared__ int m0[HIDN], m1[HIDN];
  __shared__ int c1[64], c2[64];
  __shared__ int s1[65], s2[65];
  int t = threadIdx.x;
  if (t < 64) { c1[t] = 0; c2[t] = 0; }
  __syncthreads();
  if (t < HIDN) {
    float s = 0.f;
    for (int d = 0; d < DIMN; ++d) s += M1[t * DIMN + d];
    int a = (int)(s + 0.5f) - 1;          // m0 in [0,62]
    m0[t] = a;
    atomicAdd(&c1[a], 1);
    float sb = 0.f;
    for (int o = 0; o < DIMN; ++o) sb += M3[o * HIDN + t];
    int b = 63 - (int)(sb + 0.5f);        // m1 in [0,62]
    m1[t] = b;
    atomicAdd(&c2[b], 1);
  }
  __syncthreads();
  if (t == 0) {
    int a = 0;
    for (int v = 0; v < 64; ++v) { s1[v] = a; a += c1[v]; }
    s1[64] = a;
    a = 0;
    for (int v = 0; v < 64; ++v) { s2[v] = a; a += c2[v]; }
    s2[64] = a;
  }
  __syncthreads();
  if (t < HIDN) {
    // deterministic stable rank within bucket
    int key = m0[t], rk = 0;
    for (int h = 0; h < t; ++h) rk += (m0[h] == key);
    wsi[s1[key] + rk] = t;                 // perm1
    int key2 = m1[t], rk2 = 0;
    for (int g = 0; g < t; ++g) rk2 += (m1[g] == key2);
    wsi[320 + s2[key2] + rk2] = t;         // perm2
  }
  if (t < 65) { wsi[640 + t] = s1[t]; wsi[705 + t] = s2[t]; }
}

__global__ void maf_fill(const float* __restrict__ W1, const float* __restrict__ b1,
                         const float* __restrict__ W2, const float* __restrict__ b2,
                         const float* __restrict__ W3,
                         const float* __restrict__ M1, const float* __restrict__ M2,
                         const float* __restrict__ M3,
                         const int* __restrict__ wsi, float* __restrict__ wsf) {
  int idx = blockIdx.x * blockDim.x + threadIdx.x;
  const int* p1 = wsi;
  const int* p2 = wsi + 320;
  if (idx < 20480) {                       // w1t[i][hp]
    int i = idx / 320, hp = idx % 320;
    int h = p1[hp];
    wsf[W1T_OFF + idx] = M1[h * 64 + i] * W1[h * 64 + i];
  } else if (idx < 122880) {               // w2t[hp][gp]
    int e = idx - 20480;
    int hp = e / 320, gp = e % 320;
    int h = p1[hp], g = p2[gp];
    wsf[idx] = M2[g * 320 + h] * W2[g * 320 + h];
  } else if (idx < 163840) {               // w3 interleaved: ((i*320+gp)*2 + c)
    int e = idx - 122880;
    int c = e & 1, q = e >> 1;
    int i = q / 320, gp = q % 320;
    int g = p2[gp];
    int row = i + (c ? 64 : 0);
    wsf[idx] = M3[row * 320 + g] * W3[row * 320 + g];
  } else if (idx < 164160) {
    wsf[idx] = b1[p1[idx - 163840]];
  } else if (idx < 164480) {
    wsf[idx] = b2[p2[idx - 164160]];
  }
}

#define RWS 16     // (b,t) rows per workgroup
#define H1S 328    // h1p LDS row stride (8 mod 32 -> 2-way bank aliasing = free)

__global__ __launch_bounds__(256, 4) void maf_main(
    const float* __restrict__ z, const float* __restrict__ b3,
    const float* __restrict__ wsf, const int* __restrict__ wsi,
    float* __restrict__ out) {
  __shared__ float h1p[RWS * H1S];
  __shared__ float zr[RWS * 64];
  __shared__ float xv[RWS * 64];
  __shared__ int s1[65], s2[65];

  const int tid = threadIdx.x;
  const int r = tid >> 4;    // row within block (0..15); 4 rows per wave
  const int j = tid & 15;    // lane within row-group
  const long long bt0 = (long long)blockIdx.x * RWS;

  const float* b1p = wsf + B1P_OFF;
  const float* b2p = wsf + B2P_OFF;

  // init h1 pre-activations with permuted bias
  for (int rr = 0; rr < RWS; ++rr)
    for (int c = tid; c < HIDN; c += 256)
      h1p[rr * H1S + c] = b1p[c];

  // load reversed z rows: zr[rr][i] = z[bt, 63-i]
  for (int k = tid; k < RWS * 64; k += 256) {
    int rr = k >> 6, c = k & 63;
    zr[k] = z[(bt0 + rr) * 64 + (63 - c)];
  }
  if (tid < 65) { s1[tid] = wsi[640 + tid]; s2[tid] = wsi[705 + tid]; }

  // h2 pre-activations: register-resident, lane j owns g' = j + 16k
  float h2[20];
#pragma unroll
  for (int k = 0; k < 20; ++k) h2[k] = b2p[j + 16 * k];

  float logdet = 0.f;

  for (int i = 0; i < 64; ++i) {
    __syncthreads();  // h1p suffix writes (step i-1) -> block reads (step i)
    const int p = s2[i];   // prefix end for gather == suffix start for scatter

    // ---- gather s_i, t_i over ready layer-2 prefix ----
    float ss = 0.f, tt = 0.f;
    const float* w3row = wsf + W3I_OFF + i * 640;
#pragma unroll
    for (int k = 0; k < 20; ++k) {
      int g = j + 16 * k;
      if (g < p) {
        float v = fmaxf(h2[k], 0.f);
        float2 w = *reinterpret_cast<const float2*>(w3row + 2 * g);
        ss = fmaf(w.x, v, ss);
        tt = fmaf(w.y, v, tt);
      }
    }
#pragma unroll
    for (int m = 1; m < 16; m <<= 1) {   // butterfly: all 16 lanes get full sum
      ss += __shfl_xor(ss, m);
      tt += __shfl_xor(tt, m);
    }
    ss += b3[i];
    tt += b3[64 + i];
    const float xi = (zr[(r << 6) + i] - tt) * expf(-ss);
    logdet -= ss;
    if (j == 0) xv[(r << 6) + i] = xi;

    // ---- finalize block(i) of layer-1 in-register, scatter into h2 regs ----
    const int h0 = s1[i], h1e = s1[i + 1];
    const float* w1row = wsf + W1T_OFF + i * HIDN;
    for (int hb = h0; hb < h1e; hb += 8) {
      float av[8];
#pragma unroll
      for (int u = 0; u < 8; ++u) {
        int hp = hb + u;
        int hpc = hp < h1e ? hp : h1e - 1;
        float a = fmaf(w1row[hpc], xi, h1p[r * H1S + hpc]);
        av[u] = (hp < h1e) ? fmaxf(a, 0.f) : 0.f;
      }
#pragma unroll
      for (int k = 0; k < 20; ++k) {
        int g = j + 16 * k;
        if (g >= p) {                      // suffix: m1[g'] >= i
          float acc = h2[k];
#pragma unroll
          for (int u = 0; u < 8; ++u) {
            int hp = hb + u;
            int hpc = hp < h1e ? hp : h1e - 1;
            acc = fmaf(wsf[W2T_OFF + hpc * HIDN + g], av[u], acc);
          }
          h2[k] = acc;
        }
      }
    }

    // ---- incremental layer-1 update for suffix (excluding finalized block) ----
    for (int hp = s1[i + 1] + j; hp < HIDN; hp += 16) {
      h1p[r * H1S + hp] = fmaf(w1row[hp], xi, h1p[r * H1S + hp]);
    }
  }

  __syncthreads();
  // write x (clipped)
  for (int k = tid; k < RWS * 64; k += 256) {
    float v = xv[k];
    v = fminf(fmaxf(v, -100.f), 100.f);
    out[bt0 * 64 + k] = v;
  }
  // write log_det (clipped)
  if (j == 0) {
    float v = fminf(fmaxf(logdet, -100.f), 100.f);
    out[4194304LL + bt0 + r] = v;
  }
}

extern "C" void kernel_launch(void* const* d_in, const int* in_sizes, int n_in,
                              void* d_out, int out_size, void* d_ws, size_t ws_size,
                              hipStream_t stream) {
  const float* z  = (const float*)d_in[0];
  const float* W1 = (const float*)d_in[1];
  const float* b1 = (const float*)d_in[2];
  const float* W2 = (const float*)d_in[3];
  const float* b2 = (const float*)d_in[4];
  const float* W3 = (const float*)d_in[5];
  const float* b3 = (const float*)d_in[6];
  const float* M1 = (const float*)d_in[7];
  const float* M2 = (const float*)d_in[8];
  const float* M3 = (const float*)d_in[9];
  float* out = (float*)d_out;
  float* wsf = (float*)d_ws;
  int* wsi = (int*)((char*)d_ws + (size_t)FTOT * sizeof(float));

  if (ws_size < (size_t)FTOT * sizeof(float) + 770 * sizeof(int)) return;

  maf_setup<<<1, 320, 0, stream>>>(M1, M3, wsi);
  maf_fill<<<(164480 + 255) / 256, 256, 0, stream>>>(W1, b1, W2, b2, W3, M1, M2, M3, wsi, wsf);
  maf_main<<<4096, 256, 0, stream>>>(z, b3, wsf, wsi, out);
}